// Round 8
// baseline (147.397 us; speedup 1.0000x reference)
//
#include <hip/hip_runtime.h>
#include <math.h>

typedef __attribute__((ext_vector_type(8))) __bf16 bf16x8;
typedef __attribute__((ext_vector_type(4))) __bf16 bf16x4v;
typedef __attribute__((ext_vector_type(4))) float f32x4;

#define N_TOK  4096
#define C_DIM  1024
#define N_EXP  8
#define CAP    4096

// workspace layout (bytes). ws_size ~= 256 MiB (poison-fill WRITE_SIZE evidence).
// NOTE round-3 postmortem: '<<' binds looser than '+' — keep offsets parenthesized.
#define WS_CNT    0                                   // 32 B
#define WS_PERM   32768                               // 128 KB: per-expert slot lists
#define WS_XB     ((size_t)1 << 20)                   // 8 MB: x in bf16
#define WS_WT     (WS_XB + ((size_t)8 << 20))         // 16 MB: W^T bf16

// async global->LDS, 16B per lane. LDS dest is wave-uniform base + lane*16.
#define GLD16(g, l)                                                        \
  __builtin_amdgcn_global_load_lds(                                        \
      (const __attribute__((address_space(1))) void*)(g),                  \
      (__attribute__((address_space(3))) void*)(l), 16, 0, 0)

// ---------------------------------------------------------------------------
// prep: fused router (blocks 0..255) + W transpose/bf16 (blocks 256..8447).
// Router blocks also build the per-expert slot lists (LDS-aggregated counts
// -> 8 spread global atomics per block; cnt pre-zeroed by a 32 B memset).
// ---------------------------------------------------------------------------
__global__ __launch_bounds__(256)
void prep_kernel(const float* __restrict__ x, const float* __restrict__ wg,
                 const float* __restrict__ bias, const float* __restrict__ W,
                 __bf16* __restrict__ xb, float* __restrict__ probs,
                 __bf16* __restrict__ Wt, int* __restrict__ cnt,
                 int* __restrict__ perm) {
  __shared__ __align__(16) char smem[32768];
  __shared__ int lcnt[N_EXP], base[N_EXP];
  const int tid = threadIdx.x;

  if (blockIdx.x < 256) {
    // ---------------- router ----------------
    float (*wgT)[C_DIM] = (float (*)[C_DIM])smem;   // [N_EXP][C_DIM], 32 KB
    if (tid < N_EXP) lcnt[tid] = 0;

#pragma unroll
    for (int i = 0; i < 8; ++i) {
      const float4 v = ((const float4*)wg)[i * 256 + tid];
      const int f = (i * 256 + tid) * 4;
      const int c = f >> 3;
      const int e = f & 7;
      wgT[e][c] = v.x; wgT[e + 1][c] = v.y; wgT[e + 2][c] = v.z; wgT[e + 3][c] = v.w;
    }
    __syncthreads();

    const int lane = tid & 63;
    const int wv   = tid >> 6;
    int re0[4], re1[4], rs0[4], rs1[4];   // lane0-valid per s

#pragma unroll
    for (int s = 0; s < 4; ++s) {
      const int t = blockIdx.x * 16 + wv * 4 + s;
      const float4* xrow = (const float4*)(x + (size_t)t * C_DIM);
      float acc[N_EXP];
#pragma unroll
      for (int e = 0; e < N_EXP; ++e) acc[e] = 0.f;

#pragma unroll
      for (int j = 0; j < 4; ++j) {
        const int c4 = j * 64 + lane;
        const float4 v = xrow[c4];
        bf16x4v bv = { (__bf16)v.x, (__bf16)v.y, (__bf16)v.z, (__bf16)v.w };
        *(bf16x4v*)(xb + (size_t)t * C_DIM + c4 * 4) = bv;
#pragma unroll
        for (int e = 0; e < N_EXP; ++e) {
          const float4 w = *(const float4*)&wgT[e][c4 * 4];
          acc[e] += v.x * w.x + v.y * w.y + v.z * w.z + v.w * w.w;
        }
      }

#pragma unroll
      for (int off = 32; off >= 1; off >>= 1) {
#pragma unroll
        for (int e = 0; e < N_EXP; ++e) acc[e] += __shfl_xor(acc[e], off, 64);
      }

      if (lane == 0) {
        float l[N_EXP];
#pragma unroll
        for (int e = 0; e < N_EXP; ++e) l[e] = acc[e] + bias[e];
        int e0 = 0;
#pragma unroll
        for (int e = 1; e < N_EXP; ++e) if (l[e] > l[e0]) e0 = e;
        int e1 = (e0 == 0) ? 1 : 0;
#pragma unroll
        for (int e = 0; e < N_EXP; ++e) if (e != e0 && l[e] > l[e1]) e1 = e;
        const float p0 = 1.f / (1.f + expf(l[e1] - l[e0]));
        probs[t * 2]     = p0;
        probs[t * 2 + 1] = 1.f - p0;
        re0[s] = e0; re1[s] = e1;
        rs0[s] = atomicAdd(&lcnt[e0], 1);
        rs1[s] = atomicAdd(&lcnt[e1], 1);
      }
    }
    __syncthreads();
    if (tid < N_EXP) base[tid] = atomicAdd(&cnt[tid], lcnt[tid]);
    __syncthreads();
    if (lane == 0) {
#pragma unroll
      for (int s = 0; s < 4; ++s) {
        const int t = blockIdx.x * 16 + wv * 4 + s;
        perm[re0[s] * CAP + base[re0[s]] + rs0[s]] = t * 2;
        perm[re1[s] * CAP + base[re1[s]] + rs1[s]] = t * 2 + 1;
      }
    }
  } else {
    // ---------------- W transpose + bf16 convert ----------------
    __bf16 (*tile)[33] = (__bf16 (*)[33])smem;      // [32][33]
    const int b  = blockIdx.x - 256;
    const int e  = b >> 10;
    const int r  = b & 1023;
    const int i0 = (r >> 5) * 32;
    const int o0 = (r & 31) * 32;
    const float* We  = W  + (size_t)e * C_DIM * C_DIM;
    __bf16*      Wte = Wt + (size_t)e * C_DIM * C_DIM;
    const int tx = tid & 31, ty = tid >> 5;
#pragma unroll
    for (int j = 0; j < 32; j += 8)
      tile[ty + j][tx] = (__bf16)We[(size_t)(i0 + ty + j) * C_DIM + o0 + tx];
    __syncthreads();
#pragma unroll
    for (int j = 0; j < 32; j += 8)
      Wte[(size_t)(o0 + ty + j) * C_DIM + i0 + tx] = tile[tx][ty + j];
  }
}

// ---------------------------------------------------------------------------
// Grouped GEMM, round 8: 64m x 128n tile, TWO waves (128 threads), each wave
// 64m x 64n via 4x4 of 16x16x32 bf16 MFMA (round-5-validated layout).
// Rationale: the gemm is LDS-read-BW bound; bytes/mfma = 1KB*(1/4+1/4) =
// 0.5 KB here vs 1.5 KB for round-7's 1x2 of 32x32 -> fragment traffic
// 806 -> 540 MB while keeping ~1056 active blocks (4.1/CU). BK=64,
// global_load_lds staging, XOR chunk swizzle (row r's 8x16B chunks permuted
// by r&7). Epilogue: bf16 stores into slot buffer packed in d_out's y
// region: token t's 4 KiB = [buf0[t] | buf1[t]].
// ---------------------------------------------------------------------------
__global__ __launch_bounds__(128, 4)
void moe_gemm(const __bf16* __restrict__ xb, const __bf16* __restrict__ Wt,
              const int* __restrict__ cnt, const int* __restrict__ perm,
              __bf16* __restrict__ buf) {
  const int gid = blockIdx.x;
  const int e   = gid & 7;
  const int n0  = ((gid >> 3) & 7) * 128;
  const int m0  = (gid >> 6) * 64;
  const int count = cnt[e];
  if (m0 >= count) return;

  const int*    permE = perm + e * CAP;
  const __bf16* We    = Wt + (size_t)e * C_DIM * C_DIM;

  __shared__ char AsB[8192];    // 64 rows  x 128 B (64 bf16), chunk-swizzled
  __shared__ char BsB[16384];   // 128 rows x 128 B

  const int tid  = threadIdx.x;         // 0..127
  const int lane = tid & 63;
  const int wv   = tid >> 6;            // wave 0/1 -> n-half
  const int nw   = wv * 64;
  const int l16 = lane & 15, quad = lane >> 4;

  // staging: one GLD16 round covers 16 rows (128 thr x 16 B = 2 KB);
  // thread -> row = q*16 + (tid>>3), chunk = (tid&7) ^ (row&7).
  const int rsub  = tid >> 3;           // 0..15
  const int chunk = (tid & 7) ^ (rsub & 7);
  int tk[4];
#pragma unroll
  for (int q = 0; q < 4; ++q) {
    const int i = m0 + q * 16 + rsub;
    tk[q] = (i < count) ? (permE[i] >> 1) : 0;
  }
  const char* gB = (const char*)We + (size_t)(n0 + rsub) * 2048 + chunk * 16;
  // wave-uniform LDS bases: each round's 1024 B half belongs to one wave
  char* ldsA = AsB + wv * 1024;         // + q*2048
  char* ldsB = BsB + wv * 1024;         // + q*2048

  f32x4 acc[4][4];
  const f32x4 zero = {0.f, 0.f, 0.f, 0.f};
#pragma unroll
  for (int mi = 0; mi < 4; ++mi)
#pragma unroll
    for (int ni = 0; ni < 4; ++ni) acc[mi][ni] = zero;

  for (int kt = 0; kt < 16; ++kt) {
    const int kb = kt * 128;   // byte offset along K (64 bf16)
#pragma unroll
    for (int q = 0; q < 4; ++q)      // A: 64 rows = 4 rounds
      GLD16((const char*)xb + (size_t)tk[q] * 2048 + kb + chunk * 16,
            ldsA + q * 2048);
#pragma unroll
    for (int q = 0; q < 8; ++q)      // B: 128 rows = 8 rounds
      GLD16(gB + (size_t)q * 16 * 2048 + kb, ldsB + q * 2048);
    __syncthreads();

#pragma unroll
    for (int ks = 0; ks < 2; ++ks) {
      bf16x8 af[4], bfr[4];
#pragma unroll
      for (int mi = 0; mi < 4; ++mi) {
        const int rA = mi * 16 + l16;
        af[mi] = *(const bf16x8*)(AsB + rA * 128 +
                                  (((ks * 4 + quad) ^ (rA & 7)) << 4));
      }
#pragma unroll
      for (int ni = 0; ni < 4; ++ni) {
        const int rB = nw + ni * 16 + l16;
        bfr[ni] = *(const bf16x8*)(BsB + rB * 128 +
                                   (((ks * 4 + quad) ^ (rB & 7)) << 4));
      }
#pragma unroll
      for (int mi = 0; mi < 4; ++mi)
#pragma unroll
        for (int ni = 0; ni < 4; ++ni)
          acc[mi][ni] = __builtin_amdgcn_mfma_f32_16x16x32_bf16(
              af[mi], bfr[ni], acc[mi][ni], 0, 0, 0);
    }
    __syncthreads();
  }

  // epilogue: C/D layout col = lane&15, row = quad*4 + reg (validated r1-r5)
#pragma unroll
  for (int mi = 0; mi < 4; ++mi) {
#pragma unroll
    for (int r = 0; r < 4; ++r) {
      const int i = m0 + mi * 16 + quad * 4 + r;
      if (i < count) {
        const int pe = permE[i];
        __bf16* orow = buf + (size_t)(pe >> 1) * 2048 + (pe & 1) * 1024 +
                       n0 + nw + l16;
#pragma unroll
        for (int ni = 0; ni < 4; ++ni)
          orow[ni * 16] = (__bf16)acc[mi][ni][r];
      }
    }
  }
}

// ---------------------------------------------------------------------------
// Combine, IN PLACE: block t owns y[t]'s 4 KiB = [buf0[t] | buf1[t]] bf16.
// Load both halves, barrier (drains vmcnt), overwrite with fp32 y.
// ---------------------------------------------------------------------------
__global__ __launch_bounds__(256)
void combine(const float* __restrict__ probs, float* __restrict__ y) {
  const int t = blockIdx.x;
  const int c = threadIdx.x * 4;
  const __bf16* bt = (const __bf16*)(y + (size_t)t * C_DIM);
  const bf16x4v b0 = *(const bf16x4v*)(bt + c);
  const bf16x4v b1 = *(const bf16x4v*)(bt + 1024 + c);
  const float p0 = probs[2 * t], p1 = probs[2 * t + 1];
  __syncthreads();   // all reads of this block's region complete before writes
  float4 o = { p0 * (float)b0[0] + p1 * (float)b1[0],
               p0 * (float)b0[1] + p1 * (float)b1[1],
               p0 * (float)b0[2] + p1 * (float)b1[2],
               p0 * (float)b0[3] + p1 * (float)b1[3] };
  *(float4*)(y + (size_t)t * C_DIM + c) = o;
}

extern "C" void kernel_launch(void* const* d_in, const int* in_sizes, int n_in,
                              void* d_out, int out_size, void* d_ws, size_t ws_size,
                              hipStream_t stream) {
  const float* x    = (const float*)d_in[0];
  const float* wg   = (const float*)d_in[1];
  const float* bias = (const float*)d_in[2];
  const float* wcfc = (const float*)d_in[3];

  float* y     = (float*)d_out;
  float* probs = y + (size_t)N_TOK * C_DIM;
  __bf16* buf  = (__bf16*)d_out;         // slot buffers packed in y region

  char* ws   = (char*)d_ws;
  int*    cnt  = (int*)(ws + WS_CNT);
  int*    perm = (int*)(ws + WS_PERM);
  __bf16* xb   = (__bf16*)(ws + WS_XB);
  __bf16* Wt   = (__bf16*)(ws + WS_WT);

  hipMemsetAsync(cnt, 0, N_EXP * sizeof(int), stream);

  prep_kernel<<<256 + 8192, 256, 0, stream>>>(x, wg, bias, wcfc, xb, probs,
                                              Wt, cnt, perm);
  moe_gemm<<<8 * 8 * 64, 128, 0, stream>>>(xb, Wt, cnt, perm, buf);
  combine<<<N_TOK, 256, 0, stream>>>(probs, y);
}

// Round 9
// 139.497 us; speedup vs baseline: 1.0566x; 1.0566x over previous
//
#include <hip/hip_runtime.h>
#include <math.h>

typedef __attribute__((ext_vector_type(8))) __bf16 bf16x8;
typedef __attribute__((ext_vector_type(4))) __bf16 bf16x4v;
typedef __attribute__((ext_vector_type(4))) float f32x4;

#define N_TOK  4096
#define C_DIM  1024
#define N_EXP  8
#define CAP    4096

// workspace layout (bytes). ws_size ~= 256 MiB (poison-fill WRITE_SIZE evidence).
// NOTE round-3 postmortem: '<<' binds looser than '+' — keep offsets parenthesized.
#define WS_CNT    0                                   // 32 B
#define WS_PERM   32768                               // 128 KB: per-expert slot lists
#define WS_XB     ((size_t)1 << 20)                   // 8 MB: x in bf16
#define WS_WT     (WS_XB + ((size_t)8 << 20))         // 16 MB: W^T bf16
#define WS_P0     (WS_WT + ((size_t)16 << 20))        // 16 MB: K-half-0 partials (bf16)
#define WS_P1     (WS_P0 + ((size_t)16 << 20))        // 16 MB: K-half-1 partials

// async global->LDS, 16B per lane. LDS dest is wave-uniform base + lane*16.
#define GLD16(g, l)                                                        \
  __builtin_amdgcn_global_load_lds(                                        \
      (const __attribute__((address_space(1))) void*)(g),                  \
      (__attribute__((address_space(3))) void*)(l), 16, 0, 0)

// ---------------------------------------------------------------------------
// prep: fused router (blocks 0..255) + W transpose/bf16 (blocks 256..8447).
// Router blocks also build the per-expert slot lists (LDS-aggregated counts
// -> 8 spread global atomics per block; cnt pre-zeroed by a 32 B memset).
// ---------------------------------------------------------------------------
__global__ __launch_bounds__(256)
void prep_kernel(const float* __restrict__ x, const float* __restrict__ wg,
                 const float* __restrict__ bias, const float* __restrict__ W,
                 __bf16* __restrict__ xb, float* __restrict__ probs,
                 __bf16* __restrict__ Wt, int* __restrict__ cnt,
                 int* __restrict__ perm) {
  __shared__ __align__(16) char smem[32768];
  __shared__ int lcnt[N_EXP], base[N_EXP];
  const int tid = threadIdx.x;

  if (blockIdx.x < 256) {
    // ---------------- router ----------------
    float (*wgT)[C_DIM] = (float (*)[C_DIM])smem;   // [N_EXP][C_DIM], 32 KB
    if (tid < N_EXP) lcnt[tid] = 0;

#pragma unroll
    for (int i = 0; i < 8; ++i) {
      const float4 v = ((const float4*)wg)[i * 256 + tid];
      const int f = (i * 256 + tid) * 4;
      const int c = f >> 3;
      const int e = f & 7;
      wgT[e][c] = v.x; wgT[e + 1][c] = v.y; wgT[e + 2][c] = v.z; wgT[e + 3][c] = v.w;
    }
    __syncthreads();

    const int lane = tid & 63;
    const int wv   = tid >> 6;
    int re0[4], re1[4], rs0[4], rs1[4];   // lane0-valid per s

#pragma unroll
    for (int s = 0; s < 4; ++s) {
      const int t = blockIdx.x * 16 + wv * 4 + s;
      const float4* xrow = (const float4*)(x + (size_t)t * C_DIM);
      float acc[N_EXP];
#pragma unroll
      for (int e = 0; e < N_EXP; ++e) acc[e] = 0.f;

#pragma unroll
      for (int j = 0; j < 4; ++j) {
        const int c4 = j * 64 + lane;
        const float4 v = xrow[c4];
        bf16x4v bv = { (__bf16)v.x, (__bf16)v.y, (__bf16)v.z, (__bf16)v.w };
        *(bf16x4v*)(xb + (size_t)t * C_DIM + c4 * 4) = bv;
#pragma unroll
        for (int e = 0; e < N_EXP; ++e) {
          const float4 w = *(const float4*)&wgT[e][c4 * 4];
          acc[e] += v.x * w.x + v.y * w.y + v.z * w.z + v.w * w.w;
        }
      }

#pragma unroll
      for (int off = 32; off >= 1; off >>= 1) {
#pragma unroll
        for (int e = 0; e < N_EXP; ++e) acc[e] += __shfl_xor(acc[e], off, 64);
      }

      if (lane == 0) {
        float l[N_EXP];
#pragma unroll
        for (int e = 0; e < N_EXP; ++e) l[e] = acc[e] + bias[e];
        int e0 = 0;
#pragma unroll
        for (int e = 1; e < N_EXP; ++e) if (l[e] > l[e0]) e0 = e;
        int e1 = (e0 == 0) ? 1 : 0;
#pragma unroll
        for (int e = 0; e < N_EXP; ++e) if (e != e0 && l[e] > l[e1]) e1 = e;
        const float p0 = 1.f / (1.f + expf(l[e1] - l[e0]));
        probs[t * 2]     = p0;
        probs[t * 2 + 1] = 1.f - p0;
        re0[s] = e0; re1[s] = e1;
        rs0[s] = atomicAdd(&lcnt[e0], 1);
        rs1[s] = atomicAdd(&lcnt[e1], 1);
      }
    }
    __syncthreads();
    if (tid < N_EXP) base[tid] = atomicAdd(&cnt[tid], lcnt[tid]);
    __syncthreads();
    if (lane == 0) {
#pragma unroll
      for (int s = 0; s < 4; ++s) {
        const int t = blockIdx.x * 16 + wv * 4 + s;
        perm[re0[s] * CAP + base[re0[s]] + rs0[s]] = t * 2;
        perm[re1[s] * CAP + base[re1[s]] + rs1[s]] = t * 2 + 1;
      }
    }
  } else {
    // ---------------- W transpose + bf16 convert ----------------
    __bf16 (*tile)[33] = (__bf16 (*)[33])smem;      // [32][33]
    const int b  = blockIdx.x - 256;
    const int e  = b >> 10;
    const int r  = b & 1023;
    const int i0 = (r >> 5) * 32;
    const int o0 = (r & 31) * 32;
    const float* We  = W  + (size_t)e * C_DIM * C_DIM;
    __bf16*      Wte = Wt + (size_t)e * C_DIM * C_DIM;
    const int tx = tid & 31, ty = tid >> 5;
#pragma unroll
    for (int j = 0; j < 32; j += 8)
      tile[ty + j][tx] = (__bf16)We[(size_t)(i0 + ty + j) * C_DIM + o0 + tx];
    __syncthreads();
#pragma unroll
    for (int j = 0; j < 32; j += 8)
      Wte[(size_t)(o0 + ty + j) * C_DIM + i0 + tx] = tile[tx][ty + j];
  }
}

// ---------------------------------------------------------------------------
// Grouped GEMM, round 9: SPLIT-K x2. 128m x 128n tile, 256 threads (4 waves,
// wave = 64x64 via 4x4 of 16x16x32 — the best fragment-traffic/FLOP tile,
// validated r1-r5), each block computes one K-half (512). R8 showed the gemm
// is latency-bound (MfmaUtil 14%, VALUBusy 19%, occ 11%, conflicts 0): the
// lever is resident waves. Split-K doubles active blocks to ~1024 (4/CU,
// 16 waves/CU) and halves per-block barrier drains (8 iters).
// XOR chunk swizzle on the GLOBAL address (LDS writes stay lane-sequential;
// slot s of row r holds global chunk s^(r&7)). Partials stored bf16 into
// P0/P1 (ws): token t's 4 KiB = [choice0 | choice1].
// ---------------------------------------------------------------------------
__global__ __launch_bounds__(256)
void moe_gemm(const __bf16* __restrict__ xb, const __bf16* __restrict__ Wt,
              const int* __restrict__ cnt, const int* __restrict__ perm,
              __bf16* __restrict__ P0, __bf16* __restrict__ P1) {
  const int gid = blockIdx.x;
  const int e   = gid & 7;
  const int n0  = ((gid >> 3) & 7) * 128;
  const int kh  = (gid >> 6) & 1;
  const int m0  = (gid >> 7) * 128;      // up to 32 m-tiles (CAP/128)
  const int count = cnt[e];
  if (m0 >= count) return;
  __bf16* buf = kh ? P1 : P0;

  const int*    permE = perm + e * CAP;
  const __bf16* We    = Wt + (size_t)e * C_DIM * C_DIM;

  __shared__ char AsB[16384];   // 128 rows x 128 B (64 bf16)
  __shared__ char BsB[16384];

  const int tid  = threadIdx.x;
  const int lane = tid & 63;
  const int wv   = tid >> 6;
  const int wr = wv >> 1, wc = wv & 1;
  const int mw = wr * 64, nw = wc * 64;
  const int l16 = lane & 15, quad = lane >> 4;

  // staging: round q covers rows q*32 + rsub (rsub = tid>>3, 0..31);
  // global chunk = (tid&7) ^ (row&7); LDS write is sequential lane*16.
  const int rsub  = tid >> 3;
  const int chunk = (tid & 7) ^ (rsub & 7);
  const int khb   = kh * 1024;          // K-half byte offset within a row
  int tk[4];
#pragma unroll
  for (int q = 0; q < 4; ++q) {
    const int i = m0 + q * 32 + rsub;
    tk[q] = (i < count) ? (permE[i] >> 1) : 0;
  }
  const char* gB = (const char*)We + (size_t)(n0 + rsub) * 2048 + khb + chunk * 16;
  char* ldsA = AsB + wv * 1024;         // + q*4096; lane*16 appended by HW
  char* ldsB = BsB + wv * 1024;

  f32x4 acc[4][4];
  const f32x4 zero = {0.f, 0.f, 0.f, 0.f};
#pragma unroll
  for (int mi = 0; mi < 4; ++mi)
#pragma unroll
    for (int ni = 0; ni < 4; ++ni) acc[mi][ni] = zero;

  for (int kt = 0; kt < 8; ++kt) {
    const int kb = kt * 128;   // byte offset along this K-half (64 bf16)
#pragma unroll
    for (int q = 0; q < 4; ++q)
      GLD16((const char*)xb + (size_t)tk[q] * 2048 + khb + kb + chunk * 16,
            ldsA + q * 4096);
#pragma unroll
    for (int q = 0; q < 4; ++q)
      GLD16(gB + (size_t)q * 32 * 2048 + kb, ldsB + q * 4096);
    __syncthreads();

#pragma unroll
    for (int ks = 0; ks < 2; ++ks) {
      bf16x8 af[4], bfr[4];
#pragma unroll
      for (int mi = 0; mi < 4; ++mi) {
        const int rA = mw + mi * 16 + l16;
        af[mi] = *(const bf16x8*)(AsB + rA * 128 +
                                  (((ks * 4 + quad) ^ (rA & 7)) << 4));
      }
#pragma unroll
      for (int ni = 0; ni < 4; ++ni) {
        const int rB = nw + ni * 16 + l16;
        bfr[ni] = *(const bf16x8*)(BsB + rB * 128 +
                                   (((ks * 4 + quad) ^ (rB & 7)) << 4));
      }
#pragma unroll
      for (int mi = 0; mi < 4; ++mi)
#pragma unroll
        for (int ni = 0; ni < 4; ++ni)
          acc[mi][ni] = __builtin_amdgcn_mfma_f32_16x16x32_bf16(
              af[mi], bfr[ni], acc[mi][ni], 0, 0, 0);
    }
    __syncthreads();
  }

  // epilogue: C/D layout col = lane&15, row = quad*4 + reg (validated r1-r5)
#pragma unroll
  for (int mi = 0; mi < 4; ++mi) {
#pragma unroll
    for (int r = 0; r < 4; ++r) {
      const int i = m0 + mw + mi * 16 + quad * 4 + r;
      if (i < count) {
        const int pe = permE[i];
        __bf16* orow = buf + (size_t)(pe >> 1) * 2048 + (pe & 1) * 1024 +
                       n0 + nw + l16;
#pragma unroll
        for (int ni = 0; ni < 4; ++ni)
          orow[ni * 16] = (__bf16)acc[mi][ni][r];
      }
    }
  }
}

// ---------------------------------------------------------------------------
// Combine: y[t] = p0*(P0.c0 + P1.c0) + p1*(P0.c1 + P1.c1)
// ---------------------------------------------------------------------------
__global__ __launch_bounds__(256)
void combine(const __bf16* __restrict__ P0, const __bf16* __restrict__ P1,
             const float* __restrict__ probs, float* __restrict__ y) {
  const int t = blockIdx.x;
  const int c = threadIdx.x * 4;
  const bf16x4v a0 = *(const bf16x4v*)(P0 + (size_t)t * 2048 + c);
  const bf16x4v a1 = *(const bf16x4v*)(P0 + (size_t)t * 2048 + 1024 + c);
  const bf16x4v b0 = *(const bf16x4v*)(P1 + (size_t)t * 2048 + c);
  const bf16x4v b1 = *(const bf16x4v*)(P1 + (size_t)t * 2048 + 1024 + c);
  const float p0 = probs[2 * t], p1 = probs[2 * t + 1];
  float4 o;
#pragma unroll
  for (int j = 0; j < 4; ++j)
    ((float*)&o)[j] = p0 * ((float)a0[j] + (float)b0[j]) +
                      p1 * ((float)a1[j] + (float)b1[j]);
  *(float4*)(y + (size_t)t * C_DIM + c) = o;
}

extern "C" void kernel_launch(void* const* d_in, const int* in_sizes, int n_in,
                              void* d_out, int out_size, void* d_ws, size_t ws_size,
                              hipStream_t stream) {
  const float* x    = (const float*)d_in[0];
  const float* wg   = (const float*)d_in[1];
  const float* bias = (const float*)d_in[2];
  const float* wcfc = (const float*)d_in[3];

  float* y     = (float*)d_out;
  float* probs = y + (size_t)N_TOK * C_DIM;

  char* ws   = (char*)d_ws;
  int*    cnt  = (int*)(ws + WS_CNT);
  int*    perm = (int*)(ws + WS_PERM);
  __bf16* xb   = (__bf16*)(ws + WS_XB);
  __bf16* Wt   = (__bf16*)(ws + WS_WT);
  __bf16* P0   = (__bf16*)(ws + WS_P0);
  __bf16* P1   = (__bf16*)(ws + WS_P1);

  hipMemsetAsync(cnt, 0, N_EXP * sizeof(int), stream);

  prep_kernel<<<256 + 8192, 256, 0, stream>>>(x, wg, bias, wcfc, xb, probs,
                                              Wt, cnt, perm);
  moe_gemm<<<8 * 8 * 2 * 32, 256, 0, stream>>>(xb, Wt, cnt, perm, P0, P1);
  combine<<<N_TOK, 256, 0, stream>>>(P0, P1, probs, y);
}